// Round 17
// baseline (749.583 us; speedup 1.0000x reference)
//
#include <hip/hip_runtime.h>
#include <hip/hip_fp16.h>

#define N_LINKS 262144
#define N_PAIRS 4194304
#define F 20
#define XB 20                   // X1 fp8 row stride in BYTES (packed, no pad)
#define T_ITERS 4

#define NSB 256                 // sectors (CSR build): sector = link >> 10
#define LPS 1024                // links per sector
#define PB 256                  // partition blocks
#define PT 1024                 // partition threads
#define PCHUNK (N_PAIRS / PB)   // 16384 pairs per partition block
#define PPT (PCHUNK / PT)       // 16 pairs per thread

typedef float f32x2 __attribute__((ext_vector_type(2)));
typedef _Float16 h16x2 __attribute__((ext_vector_type(2)));

__device__ __forceinline__ float selu_f(float x) {
    const float scale = 1.0507009873554805f;
    const float scale_alpha = 1.7580993408473766f;  // scale * alpha
    return x > 0.0f ? scale * x : scale_alpha * (__expf(x) - 1.0f);
}

// Branchless selu: sa*exp(min(x,0)) - sa + s*max(x,0). Exact at x=0 (exp(0)=1).
__device__ __forceinline__ float selu_b(float x) {
    const float s = 1.0507009873554805f;
    const float sa = 1.7580993408473766f;
    const float mx = fmaxf(x, 0.0f);
    const float mn = fminf(x, 0.0f);
    return fmaf(sa, __expf(mn), fmaf(s, mx, -sa));
}

__device__ __forceinline__ float sigmoid_f(float x) {
    return 1.0f / (1.0f + __expf(-x));
}

__device__ __forceinline__ float tanh_fast(float x) {
    x = fminf(fmaxf(x, -15.0f), 15.0f);
    float e = __expf(2.0f * x);
    return (e - 1.0f) / (e + 1.0f);
}

// Pack 20 floats -> 20 fp8 e4m3 bytes, one 20B row (5 dword stores, 4B aligned).
__device__ __forceinline__ void store_row_fp8(unsigned char* rowp, const float* o1) {
    int* p = (int*)rowp;
#pragma unroll
    for (int i = 0; i < 5; ++i) {
        int w = 0;
        w = __builtin_amdgcn_cvt_pk_fp8_f32(o1[4*i+0], o1[4*i+1], w, false);
        w = __builtin_amdgcn_cvt_pk_fp8_f32(o1[4*i+2], o1[4*i+3], w, true);
        p[i] = w;
    }
}

// ---------------- CSR build (once per call; graph is static) ----------------

__global__ void __launch_bounds__(PT)
k_part(const int* __restrict__ first, const int* __restrict__ second,
       int* __restrict__ ent, int* __restrict__ ptable, int* __restrict__ sectot) {
    __shared__ int hist[NSB];
    __shared__ int cur[NSB];
    const int b = blockIdx.x;
    const int cbase = b * PCHUNK;
    const int tid = threadIdx.x;
    for (int i = tid; i < NSB; i += PT) hist[i] = 0;
    __syncthreads();
    int sv[PPT];
#pragma unroll
    for (int k = 0; k < PPT; ++k) {
        sv[k] = second[cbase + k * PT + tid];
        atomicAdd(&hist[sv[k] >> 10], 1);
    }
    __syncthreads();
    if (tid < NSB) {
        int acc = 0;
        for (int j = 0; j < tid; ++j) acc += hist[j];   // excl scan, 256 bins
        cur[tid] = acc;
        ptable[b * (NSB + 1) + tid] = acc;
        if (tid == 0) ptable[b * (NSB + 1) + NSB] = PCHUNK;
        atomicAdd(&sectot[tid], hist[tid]);
    }
    __syncthreads();
#pragma unroll
    for (int k = 0; k < PPT; ++k) {
        const int s = sv[k];
        const int f = first[cbase + k * PT + tid];
        const int pos = atomicAdd(&cur[s >> 10], 1);
        ent[cbase + pos] = f | ((s & 1023) << 18);
    }
}

__global__ void k_scan256(const int* __restrict__ sectot, int* __restrict__ sbase,
                          int* __restrict__ rs) {
    __shared__ int s[NSB];
    const int t = threadIdx.x;
    s[t] = sectot[t];
    __syncthreads();
    if (t == 0) {
        int acc = 0;
        for (int j = 0; j < NSB; ++j) { int c = s[j]; s[j] = acc; acc += c; }
    }
    __syncthreads();
    sbase[t] = s[t];
    if (t == 0) { sbase[NSB] = N_PAIRS; rs[N_LINKS] = N_PAIRS; }
}

// Degree-sort per sector; emits rank-ordered rs, lid[rank]=link, rnk[link]=rank
// (direct inverse write). srcs hold RAW link ids; k_remap converts afterwards.
__global__ void __launch_bounds__(PT)
k_build(const int* __restrict__ ptable, const int* __restrict__ sbase,
        const int* __restrict__ ent, int* __restrict__ srcs, int* __restrict__ rs,
        int* __restrict__ lid, int* __restrict__ rnk_g) {
    __shared__ int rstart[PB];
    __shared__ int rlen[PB];
    __shared__ int lcnt[LPS];
    __shared__ int cur[LPS];
    __shared__ int dhist[64];
    __shared__ int dbase[64];
    __shared__ int dcur[64];
    const int sb = blockIdx.x;
    const int tid = threadIdx.x;
    if (tid < PB) {
        const int o0 = ptable[tid * (NSB + 1) + sb];
        const int o1 = ptable[tid * (NSB + 1) + sb + 1];
        rstart[tid] = tid * PCHUNK + o0;
        rlen[tid] = o1 - o0;
    }
    lcnt[tid] = 0;                       // PT == LPS
    if (tid < 64) { dhist[tid] = 0; dcur[tid] = 0; }
    __syncthreads();
    const int wave = tid >> 6;
    const int lane = tid & 63;
    for (int j = wave; j < PB; j += (PT >> 6)) {
        const int r0 = rstart[j], rl = rlen[j];
        for (int i = lane; i < rl; i += 64)
            atomicAdd(&lcnt[(ent[r0 + i] >> 18) & 1023], 1);
    }
    __syncthreads();
    const int count = lcnt[tid];
    const int dbin = min(count, 63);
    atomicAdd(&dhist[dbin], 1);
    __syncthreads();
    if (tid == 0) {
        int acc = 0;
        for (int b = 0; b < 64; ++b) { dbase[b] = acc; acc += dhist[b]; }
    }
    __syncthreads();
    const int rank = dbase[dbin] + atomicAdd(&dcur[dbin], 1);
    lcnt[rank] = count;                  // re-key counts into rank order
    lid[sb * LPS + rank] = sb * LPS + tid;
    rnk_g[sb * LPS + tid] = sb * LPS + rank;
    __syncthreads();
    for (int off = 1; off < LPS; off <<= 1) {   // inclusive Hillis-Steele scan
        const int v = (tid >= off) ? lcnt[tid - off] : 0;
        __syncthreads();
        lcnt[tid] += v;
        __syncthreads();
    }
    const int sbb = sbase[sb];
    const int excl = lcnt[rank] - count;
    rs[sb * LPS + rank] = sbb + excl;
    cur[tid] = excl;                     // cur stays in tid (link) space
    __syncthreads();
    for (int j = wave; j < PB; j += (PT >> 6)) {
        const int r0 = rstart[j], rl = rlen[j];
        for (int i = lane; i < rl; i += 64) {
            const int e = ent[r0 + i];
            const int pos = atomicAdd(&cur[(e >> 18) & 1023], 1);
            srcs[sbb + pos] = e & 0x3FFFF;   // raw link id
        }
    }
}

// srcs: raw link id -> rank*20 (prescaled byte base into rank-space X1b).
__global__ void k_remap(int* __restrict__ srcs, const int* __restrict__ rnk) {
    const int p = blockIdx.x * blockDim.x + threadIdx.x;
    srcs[p] = rnk[srcs[p]] * 20;
}

// ---------------- per-iteration kernels ----------------

// Slot-indexed premsg (t=0): link = lid[slot]; gathers link_state row, writes
// X1b/X2h at slot (rank space) AND copies the row into state_r[slot].
__global__ void k_premsg(const float* __restrict__ link_state,
                         const int* __restrict__ lid,
                         const float* __restrict__ W_msg,
                         const float* __restrict__ b_msg,
                         unsigned char* __restrict__ X1b, __half* __restrict__ X2h,
                         float* __restrict__ state_r) {
    __shared__ float Wl[F * 2 * F];
    __shared__ float bl[F];
    for (int i = threadIdx.x; i < F * 2 * F; i += blockDim.x) Wl[i] = W_msg[i];
    if (threadIdx.x < F) bl[threadIdx.x] = b_msg[threadIdx.x];
    __syncthreads();

    const int slot = blockIdx.x * blockDim.x + threadIdx.x;
    const int link = lid[slot];

    float s[F];
    const float4* sp = (const float4*)(link_state + (size_t)link * F);
    float4* so = (float4*)(state_r + (size_t)slot * F);
#pragma unroll
    for (int i = 0; i < 5; ++i) {
        float4 v = sp[i];
        so[i] = v;
        s[4*i+0] = v.x; s[4*i+1] = v.y; s[4*i+2] = v.z; s[4*i+3] = v.w;
    }
    float o1[F], o2[F];
#pragma unroll
    for (int o = 0; o < F; ++o) {
        float a1 = bl[o], a2 = 0.0f;
#pragma unroll
        for (int k = 0; k < F; ++k) {
            a1 = fmaf(Wl[o * 2 * F + k],     s[k], a1);
            a2 = fmaf(Wl[o * 2 * F + F + k], s[k], a2);
        }
        o1[o] = a1; o2[o] = a2;
    }
    store_row_fp8(X1b + (size_t)slot * XB, o1);
    __half2* xp = (__half2*)(X2h + (size_t)slot * F);
#pragma unroll
    for (int i = 0; i < 10; ++i)
        xp[i] = __halves2half2(__float2half(o2[2*i]), __float2half(o2[2*i+1]));
}

// Gather-aggregate, 6 rank-consecutive slots per wave (degree-sorted -> equal
// degrees). Fully rank-space; X1b gathered via rank-remapped prescaled srcs.
__global__ void __launch_bounds__(256)
k_agg(const int* __restrict__ rs, const int* __restrict__ srcs,
      const unsigned char* __restrict__ X1b, const __half* __restrict__ X2h,
      float* __restrict__ agg) {
    const int wave = threadIdx.x >> 6;
    const int lane = threadIdx.x & 63;
    const int g = lane / 10;          // 0..5 active, 6 = idle (lanes 60-63)
    const int j = lane - g * 10;      // 0..9
    const int gsel = (g < 6) ? g : 5;
    const int slot = (blockIdx.x * 4 + wave) * 6 + gsel;

    const bool active = (g < 6) && (slot < N_LINKS);
    const int sc = min(slot, N_LINKS - 1);
    const int row_start = rs[sc];
    const int cnt = active ? (rs[sc + 1] - row_start) : 0;
    const int cl = (cnt > 0) ? (cnt - 1) : 0;

    const __half2 hv = *(const __half2*)(X2h + (size_t)sc * F + 2 * j);
    const float x2a = __half2float(__low2half(hv));
    const float x2b = __half2float(__high2half(hv));

    int cmax = cnt;
#pragma unroll
    for (int off = 1; off < 64; off <<= 1)
        cmax = max(cmax, __shfl_xor(cmax, off, 64));

    float acc_a = 0.0f, acc_b = 0.0f;

    for (int base = 0; base < cmax; base += 10) {
        const int sv = srcs[row_start + min(base + j, cl)];  // batch preload
#pragma unroll
        for (int r = 0; r < 10; ++r) {
            const int src = __shfl(sv, gsel * 10 + r, 64);   // prescaled rank*20
            const unsigned v = *(const unsigned short*)(X1b + src + 2 * j);
            const f32x2 xx = __builtin_amdgcn_cvt_pk_f32_fp8((int)v, false);
            const bool ok = (base + r) < cnt;
            acc_a += ok ? selu_b(xx[0] + x2a) : 0.0f;
            acc_b += ok ? selu_b(xx[1] + x2b) : 0.0f;
        }
    }
    if (active) {
        float2 o; o.x = acc_a; o.y = acc_b;
        *(float2*)(agg + (size_t)slot * F + 2 * j) = o;
    }
}

// GRU (rank space), 2 links per thread, fused next-iter premsg (flags&1) and
// feature reduce (flags&2). Weight ROWS are loaded contiguously into registers
// (ds_read_b128/b64, not per-dot2 b32) and reused for BOTH links -> LDS
// instruction count per link drops ~6.7x vs the per-element version.
__global__ void __launch_bounds__(256)
k_gru(const float* __restrict__ agg, float* __restrict__ state,
      const float* __restrict__ W_ih, const float* __restrict__ W_hh,
      const float* __restrict__ b_ih, const float* __restrict__ b_hh,
      const float* __restrict__ W_msg, const float* __restrict__ b_msg,
      unsigned char* __restrict__ X1b, __half* __restrict__ X2h,
      float* __restrict__ feature, int flags) {
    __shared__ h16x2 WiH[3 * F * 10];   // row (gate*F+o): 10 h16x2 = 20 weights
    __shared__ h16x2 WhH[3 * F * 10];
    __shared__ h16x2 WmH[F * 20];       // row o: k 0..9 = W1, 10..19 = W2
    __shared__ float bi[3 * F];
    __shared__ float bh[3 * F];
    __shared__ float bm[F];
    __shared__ float red[4 * F];
    {
        _Float16* wi = (_Float16*)WiH;
        _Float16* wh = (_Float16*)WhH;
        for (int i = threadIdx.x; i < 3 * F * F; i += 256) {
            wi[i] = (_Float16)W_ih[i];
            wh[i] = (_Float16)W_hh[i];
        }
        _Float16* wm = (_Float16*)WmH;
        for (int i = threadIdx.x; i < F * 2 * F; i += 256)
            wm[i] = (_Float16)W_msg[i];
    }
    if (threadIdx.x < 3 * F) {
        bi[threadIdx.x] = b_ih[threadIdx.x];
        bh[threadIdx.x] = b_hh[threadIdx.x];
    }
    if (threadIdx.x < F) bm[threadIdx.x] = b_msg[threadIdx.x];
    __syncthreads();

    const int l0 = (blockIdx.x * blockDim.x + threadIdx.x) * 2;

    h16x2 mh[2][10], hh[2][10];
#pragma unroll
    for (int L = 0; L < 2; ++L) {
        const float4* mp = (const float4*)(agg   + (size_t)(l0 + L) * F);
        const float4* hp = (const float4*)(state + (size_t)(l0 + L) * F);
#pragma unroll
        for (int i = 0; i < 5; ++i) {
            const float4 vm = mp[i], vh = hp[i];
            mh[L][2*i+0][0] = (_Float16)vm.x; mh[L][2*i+0][1] = (_Float16)vm.y;
            mh[L][2*i+1][0] = (_Float16)vm.z; mh[L][2*i+1][1] = (_Float16)vm.w;
            hh[L][2*i+0][0] = (_Float16)vh.x; hh[L][2*i+0][1] = (_Float16)vh.y;
            hh[L][2*i+1][0] = (_Float16)vh.z; hh[L][2*i+1][1] = (_Float16)vh.w;
        }
    }

    float hn[2][F];
#pragma unroll
    for (int o = 0; o < F; ++o) {
        float sr[2], sz[2], sni[2], snh[2];
        {   // r gate: rows loaded once, used for both links
            h16x2 wi[10], wh[10];
#pragma unroll
            for (int kk = 0; kk < 10; ++kk) {
                wi[kk] = WiH[(0*F + o) * 10 + kk];
                wh[kk] = WhH[(0*F + o) * 10 + kk];
            }
#pragma unroll
            for (int L = 0; L < 2; ++L) {
                float a = bi[o] + bh[o];
#pragma unroll
                for (int kk = 0; kk < 10; ++kk) {
                    a = __builtin_amdgcn_fdot2(wi[kk], mh[L][kk], a, false);
                    a = __builtin_amdgcn_fdot2(wh[kk], hh[L][kk], a, false);
                }
                sr[L] = a;
            }
        }
        {   // z gate
            h16x2 wi[10], wh[10];
#pragma unroll
            for (int kk = 0; kk < 10; ++kk) {
                wi[kk] = WiH[(1*F + o) * 10 + kk];
                wh[kk] = WhH[(1*F + o) * 10 + kk];
            }
#pragma unroll
            for (int L = 0; L < 2; ++L) {
                float a = bi[F + o] + bh[F + o];
#pragma unroll
                for (int kk = 0; kk < 10; ++kk) {
                    a = __builtin_amdgcn_fdot2(wi[kk], mh[L][kk], a, false);
                    a = __builtin_amdgcn_fdot2(wh[kk], hh[L][kk], a, false);
                }
                sz[L] = a;
            }
        }
        {   // n gate (i and h parts kept separate: n = tanh(gin + r*ghn))
            h16x2 wi[10], wh[10];
#pragma unroll
            for (int kk = 0; kk < 10; ++kk) {
                wi[kk] = WiH[(2*F + o) * 10 + kk];
                wh[kk] = WhH[(2*F + o) * 10 + kk];
            }
#pragma unroll
            for (int L = 0; L < 2; ++L) {
                float ai = bi[2*F + o], ah = bh[2*F + o];
#pragma unroll
                for (int kk = 0; kk < 10; ++kk) {
                    ai = __builtin_amdgcn_fdot2(wi[kk], mh[L][kk], ai, false);
                    ah = __builtin_amdgcn_fdot2(wh[kk], hh[L][kk], ah, false);
                }
                sni[L] = ai; snh[L] = ah;
            }
        }
#pragma unroll
        for (int L = 0; L < 2; ++L) {
            const float r = sigmoid_f(sr[L]);
            const float z = sigmoid_f(sz[L]);
            const float n = tanh_fast(sni[L] + r * snh[L]);
            const float hO = (float)hh[L][o >> 1][o & 1];
            hn[L][o] = (1.0f - z) * n + z * hO;
        }
    }

#pragma unroll
    for (int L = 0; L < 2; ++L) {
        float4* op = (float4*)(state + (size_t)(l0 + L) * F);
#pragma unroll
        for (int i = 0; i < 5; ++i)
            op[i] = make_float4(hn[L][4*i], hn[L][4*i+1], hn[L][4*i+2], hn[L][4*i+3]);
    }

    if (flags & 1) {  // premsg for next iteration from hn
#pragma unroll
        for (int L = 0; L < 2; ++L) {
            h16x2 hnh[10];
#pragma unroll
            for (int i = 0; i < 10; ++i) {
                hnh[i][0] = (_Float16)hn[L][2*i]; hnh[i][1] = (_Float16)hn[L][2*i+1];
            }
            float o1[F], o2[F];
#pragma unroll
            for (int o = 0; o < F; ++o) {
                h16x2 w1[10], w2[10];
#pragma unroll
                for (int kk = 0; kk < 10; ++kk) {
                    w1[kk] = WmH[o * 20 + kk];
                    w2[kk] = WmH[o * 20 + 10 + kk];
                }
                float a1 = bm[o], a2 = 0.0f;
#pragma unroll
                for (int kk = 0; kk < 10; ++kk) {
                    a1 = __builtin_amdgcn_fdot2(w1[kk], hnh[kk], a1, false);
                    a2 = __builtin_amdgcn_fdot2(w2[kk], hnh[kk], a2, false);
                }
                o1[o] = a1; o2[o] = a2;
            }
            store_row_fp8(X1b + (size_t)(l0 + L) * XB, o1);
            __half2* xp = (__half2*)(X2h + (size_t)(l0 + L) * F);
#pragma unroll
            for (int i = 0; i < 10; ++i)
                xp[i] = __halves2half2(__float2half(o2[2*i]), __float2half(o2[2*i+1]));
        }
    }

    if (flags & 2) {  // feature reduction: sum hn over all links
        float hs[F];
#pragma unroll
        for (int jj = 0; jj < F; ++jj) hs[jj] = hn[0][jj] + hn[1][jj];
#pragma unroll
        for (int off = 1; off < 64; off <<= 1) {
#pragma unroll
            for (int jj = 0; jj < F; ++jj) hs[jj] += __shfl_xor(hs[jj], off, 64);
        }
        const int lane = threadIdx.x & 63;
        const int wave = threadIdx.x >> 6;
        if (lane == 0) {
#pragma unroll
            for (int jj = 0; jj < F; ++jj) red[wave * F + jj] = hs[jj];
        }
        __syncthreads();
        if (threadIdx.x < F) {
            float s = red[threadIdx.x] + red[F + threadIdx.x] +
                      red[2 * F + threadIdx.x] + red[3 * F + threadIdx.x];
            atomicAdd(&feature[threadIdx.x], s);
        }
    }
}

__global__ void k_readout(const float* __restrict__ feature,
                          const float* __restrict__ W_r1, const float* __restrict__ b_r1,
                          const float* __restrict__ W_r2, const float* __restrict__ b_r2,
                          const float* __restrict__ W_out, const float* __restrict__ b_out,
                          float* __restrict__ out) {
    if (threadIdx.x != 0 || blockIdx.x != 0) return;
    float fv[F], h1[F], h2[F];
#pragma unroll
    for (int i = 0; i < F; ++i) fv[i] = feature[i];
#pragma unroll
    for (int o = 0; o < F; ++o) {
        float a = b_r1[o];
#pragma unroll
        for (int k = 0; k < F; ++k) a = fmaf(W_r1[o * F + k], fv[k], a);
        h1[o] = selu_f(a);
    }
#pragma unroll
    for (int o = 0; o < F; ++o) {
        float a = b_r2[o];
#pragma unroll
        for (int k = 0; k < F; ++k) a = fmaf(W_r2[o * F + k], h1[k], a);
        h2[o] = selu_f(a);
    }
    float a = b_out[0];
#pragma unroll
    for (int k = 0; k < F; ++k) a = fmaf(W_out[k], h2[k], a);
    out[0] = a;
}

extern "C" void kernel_launch(void* const* d_in, const int* in_sizes, int n_in,
                              void* d_out, int out_size, void* d_ws, size_t ws_size,
                              hipStream_t stream) {
    const float* link_state = (const float*)d_in[0];
    const int*   first      = (const int*)  d_in[1];
    const int*   second     = (const int*)  d_in[2];
    // d_in[3] = state_dim (unused)
    const float* W_msg = (const float*)d_in[4];
    const float* b_msg = (const float*)d_in[5];
    const float* W_ih  = (const float*)d_in[6];
    const float* W_hh  = (const float*)d_in[7];
    const float* b_ih  = (const float*)d_in[8];
    const float* b_hh  = (const float*)d_in[9];
    const float* W_r1  = (const float*)d_in[10];
    const float* b_r1  = (const float*)d_in[11];
    const float* W_r2  = (const float*)d_in[12];
    const float* b_r2  = (const float*)d_in[13];
    const float* W_out = (const float*)d_in[14];
    const float* b_out = (const float*)d_in[15];
    float* out = (float*)d_out;

    const size_t NF = (size_t)N_LINKS * F;
    float* state = (float*)d_ws;                            // 21 MB (rank space)
    float* agg   = state + NF;                              // 21 MB (aliases ent)
    unsigned char* X1b = (unsigned char*)(agg + NF);        // 5.25 MB (rank space)
    __half* X2h = (__half*)(X1b + (size_t)N_LINKS * XB + 64);  // 10.5 MB
    int* srcs   = (int*)(X2h + NF);                         // 16.8 MB
    int* rs     = srcs + N_PAIRS;                           // 1 MB (+1)
    int* lid    = rs + N_LINKS + 1;                         // 1 MB
    int* rnk    = lid + N_LINKS;                            // 1 MB
    float* feature = (float*)(rnk + N_LINKS);               // 128 B slot
    int* ptable = (int*)(feature + 32);                     // 256*(256+1) ints
    int* sectot = ptable + PB * (NSB + 1);                  // 256 ints
    int* sbase  = sectot + NSB;                             // 257 ints
    int* ent    = (int*)agg;    // lifetime: part..build only

    hipMemsetAsync(sectot, 0, NSB * sizeof(int), stream);
    hipMemsetAsync(feature, 0, F * sizeof(float), stream);

    k_part<<<PB, PT, 0, stream>>>(first, second, ent, ptable, sectot);
    k_scan256<<<1, NSB, 0, stream>>>(sectot, sbase, rs);
    k_build<<<NSB, PT, 0, stream>>>(ptable, sbase, ent, srcs, rs, lid, rnk);
    k_remap<<<N_PAIRS / 256, 256, 0, stream>>>(srcs, rnk);

    k_premsg<<<N_LINKS / 256, 256, 0, stream>>>(link_state, lid, W_msg, b_msg,
                                                X1b, X2h, state);

    const int aggBlocks = (N_LINKS + 23) / 24;   // 4 waves x 6 slots per block
    for (int t = 0; t < T_ITERS; ++t) {
        int flags = (t < T_ITERS - 1 ? 1 : 0) | (t == T_ITERS - 1 ? 2 : 0);
        k_agg<<<aggBlocks, 256, 0, stream>>>(rs, srcs, X1b, X2h, agg);
        k_gru<<<N_LINKS / 512, 256, 0, stream>>>(agg, state, W_ih, W_hh, b_ih, b_hh,
                                                 W_msg, b_msg, X1b, X2h,
                                                 feature, flags);
    }
    k_readout<<<1, 64, 0, stream>>>(feature, W_r1, b_r1, W_r2, b_r2, W_out, b_out, out);
}

// Round 18
// 583.661 us; speedup vs baseline: 1.2843x; 1.2843x over previous
//
#include <hip/hip_runtime.h>
#include <hip/hip_fp16.h>

#define N_LINKS 262144
#define N_PAIRS 4194304
#define F 20
#define XB 20                   // X1 fp8 row stride in BYTES (packed, no pad)
#define T_ITERS 4

#define NSB 256                 // sectors (CSR build): sector = link >> 10
#define LPS 1024                // links per sector
#define PB 256                  // partition blocks
#define PT 1024                 // partition threads
#define PCHUNK (N_PAIRS / PB)   // 16384 pairs per partition block
#define PPT (PCHUNK / PT)       // 16 pairs per thread

typedef float f32x2 __attribute__((ext_vector_type(2)));
typedef _Float16 h16x2 __attribute__((ext_vector_type(2)));

__device__ __forceinline__ float selu_f(float x) {
    const float scale = 1.0507009873554805f;
    const float scale_alpha = 1.7580993408473766f;  // scale * alpha
    return x > 0.0f ? scale * x : scale_alpha * (__expf(x) - 1.0f);
}

// Branchless selu: sa*exp(min(x,0)) - sa + s*max(x,0). Exact at x=0 (exp(0)=1).
__device__ __forceinline__ float selu_b(float x) {
    const float s = 1.0507009873554805f;
    const float sa = 1.7580993408473766f;
    const float mx = fmaxf(x, 0.0f);
    const float mn = fminf(x, 0.0f);
    return fmaf(sa, __expf(mn), fmaf(s, mx, -sa));
}

__device__ __forceinline__ float sigmoid_f(float x) {
    return 1.0f / (1.0f + __expf(-x));
}

__device__ __forceinline__ float tanh_fast(float x) {
    x = fminf(fmaxf(x, -15.0f), 15.0f);
    float e = __expf(2.0f * x);
    return (e - 1.0f) / (e + 1.0f);
}

// Pack 20 floats -> 20 fp8 e4m3 bytes, one 20B row (5 dword stores, 4B aligned).
__device__ __forceinline__ void store_row_fp8(unsigned char* rowp, const float* o1) {
    int* p = (int*)rowp;
#pragma unroll
    for (int i = 0; i < 5; ++i) {
        int w = 0;
        w = __builtin_amdgcn_cvt_pk_fp8_f32(o1[4*i+0], o1[4*i+1], w, false);
        w = __builtin_amdgcn_cvt_pk_fp8_f32(o1[4*i+2], o1[4*i+3], w, true);
        p[i] = w;
    }
}

// ---------------- CSR build (once per call; graph is static) ----------------

// Each block counting-sorts its 16K-pair chunk by sector into its OWN window
// of `ent`. Emits per-(block,sector) offsets + global sector totals.
// Entry = {first:18 | link-within-sector:10}.
__global__ void __launch_bounds__(PT)
k_part(const int* __restrict__ first, const int* __restrict__ second,
       int* __restrict__ ent, int* __restrict__ ptable, int* __restrict__ sectot) {
    __shared__ int hist[NSB];
    __shared__ int cur[NSB];
    const int b = blockIdx.x;
    const int cbase = b * PCHUNK;
    const int tid = threadIdx.x;
    for (int i = tid; i < NSB; i += PT) hist[i] = 0;
    __syncthreads();
    int sv[PPT];
#pragma unroll
    for (int k = 0; k < PPT; ++k) {
        sv[k] = second[cbase + k * PT + tid];
        atomicAdd(&hist[sv[k] >> 10], 1);
    }
    __syncthreads();
    if (tid < NSB) {
        int acc = 0;
        for (int j = 0; j < tid; ++j) acc += hist[j];   // excl scan, 256 bins
        cur[tid] = acc;
        ptable[b * (NSB + 1) + tid] = acc;
        if (tid == 0) ptable[b * (NSB + 1) + NSB] = PCHUNK;
        atomicAdd(&sectot[tid], hist[tid]);
    }
    __syncthreads();
#pragma unroll
    for (int k = 0; k < PPT; ++k) {
        const int s = sv[k];
        const int f = first[cbase + k * PT + tid];
        const int pos = atomicAdd(&cur[s >> 10], 1);
        ent[cbase + pos] = f | ((s & 1023) << 18);
    }
}

// Exact exclusive scan of 256 sector totals -> sector bases (srcs contiguous).
__global__ void k_scan256(const int* __restrict__ sectot, int* __restrict__ sbase,
                          int* __restrict__ rs) {
    __shared__ int s[NSB];
    const int t = threadIdx.x;
    s[t] = sectot[t];
    __syncthreads();
    if (t == 0) {
        int acc = 0;
        for (int j = 0; j < NSB; ++j) { int c = s[j]; s[j] = acc; acc += c; }
    }
    __syncthreads();
    sbase[t] = s[t];
    if (t == 0) { sbase[NSB] = N_PAIRS; rs[N_LINKS] = N_PAIRS; }
}

// One block per sector: gather the sector's entries from the table-addressed
// runs, per-link LDS histogram, DEGREE-SORT the 1024 links (counting sort,
// 64 bins) -> rank order. rs/srcs are emitted in rank order; lid[rank] gives
// the true link id. Waves in k_agg then see near-uniform degrees.
// srcs entries are PRESCALED: src * 20 (byte base into X1b).
__global__ void __launch_bounds__(PT)
k_build(const int* __restrict__ ptable, const int* __restrict__ sbase,
        const int* __restrict__ ent, int* __restrict__ srcs, int* __restrict__ rs,
        int* __restrict__ lid) {
    __shared__ int rstart[PB];
    __shared__ int rlen[PB];
    __shared__ int lcnt[LPS];
    __shared__ int cur[LPS];
    __shared__ int dhist[64];
    __shared__ int dbase[64];
    __shared__ int dcur[64];
    const int sb = blockIdx.x;
    const int tid = threadIdx.x;
    if (tid < PB) {
        const int o0 = ptable[tid * (NSB + 1) + sb];
        const int o1 = ptable[tid * (NSB + 1) + sb + 1];
        rstart[tid] = tid * PCHUNK + o0;
        rlen[tid] = o1 - o0;
    }
    lcnt[tid] = 0;                       // PT == LPS
    if (tid < 64) { dhist[tid] = 0; dcur[tid] = 0; }
    __syncthreads();
    const int wave = tid >> 6;
    const int lane = tid & 63;
    for (int j = wave; j < PB; j += (PT >> 6)) {
        const int r0 = rstart[j], rl = rlen[j];
        for (int i = lane; i < rl; i += 64)
            atomicAdd(&lcnt[(ent[r0 + i] >> 18) & 1023], 1);
    }
    __syncthreads();
    const int count = lcnt[tid];
    const int dbin = min(count, 63);
    atomicAdd(&dhist[dbin], 1);
    __syncthreads();
    if (tid == 0) {
        int acc = 0;
        for (int b = 0; b < 64; ++b) { dbase[b] = acc; acc += dhist[b]; }
    }
    __syncthreads();
    const int rank = dbase[dbin] + atomicAdd(&dcur[dbin], 1);
    lcnt[rank] = count;                  // re-key counts into rank order
    lid[sb * LPS + rank] = sb * LPS + tid;
    __syncthreads();
    for (int off = 1; off < LPS; off <<= 1) {   // inclusive Hillis-Steele scan
        const int v = (tid >= off) ? lcnt[tid - off] : 0;
        __syncthreads();
        lcnt[tid] += v;
        __syncthreads();
    }
    const int sbb = sbase[sb];
    const int excl = lcnt[rank] - count;
    rs[sb * LPS + rank] = sbb + excl;
    cur[tid] = excl;                     // cur stays in tid (link) space
    __syncthreads();
    for (int j = wave; j < PB; j += (PT >> 6)) {
        const int r0 = rstart[j], rl = rlen[j];
        for (int i = lane; i < rl; i += 64) {
            const int e = ent[r0 + i];
            const int pos = atomicAdd(&cur[(e >> 18) & 1023], 1);
            srcs[sbb + pos] = (e & 0x3FFFF) * 20;   // prescaled byte base
        }
    }
}

// ---------------- per-iteration kernels ----------------

// X1b[l] = fp8(W1 @ state[l] + b_msg), 20B rows ; X2h[l] = fp16(W2 @ state[l])
__global__ void k_premsg(const float* __restrict__ state,
                         const float* __restrict__ W_msg,
                         const float* __restrict__ b_msg,
                         unsigned char* __restrict__ X1b, __half* __restrict__ X2h) {
    __shared__ float Wl[F * 2 * F];
    __shared__ float bl[F];
    for (int i = threadIdx.x; i < F * 2 * F; i += blockDim.x) Wl[i] = W_msg[i];
    if (threadIdx.x < F) bl[threadIdx.x] = b_msg[threadIdx.x];
    __syncthreads();

    int l = blockIdx.x * blockDim.x + threadIdx.x;

    float s[F];
    const float4* sp = (const float4*)(state + (size_t)l * F);
#pragma unroll
    for (int i = 0; i < 5; ++i) {
        float4 v = sp[i];
        s[4*i+0] = v.x; s[4*i+1] = v.y; s[4*i+2] = v.z; s[4*i+3] = v.w;
    }
    float o1[F], o2[F];
#pragma unroll
    for (int o = 0; o < F; ++o) {
        float a1 = bl[o], a2 = 0.0f;
#pragma unroll
        for (int k = 0; k < F; ++k) {
            a1 = fmaf(Wl[o * 2 * F + k],     s[k], a1);
            a2 = fmaf(Wl[o * 2 * F + F + k], s[k], a2);
        }
        o1[o] = a1; o2[o] = a2;
    }
    store_row_fp8(X1b + (size_t)l * XB, o1);
    __half2* xp = (__half2*)(X2h + (size_t)l * F);
#pragma unroll
    for (int i = 0; i < 10; ++i)
        xp[i] = __halves2half2(__float2half(o2[2*i]), __float2half(o2[2*i+1]));
}

// Gather-aggregate, 6 RANK-consecutive links per wave (degree-sorted -> the 6
// links have near-equal degree, so cmax ~= cnt and batch slots are ~95% used).
// lane = g*10 + j; group g owns rank slot lb+g (true link = lid[slot]); lane j
// accumulates features 2j,2j+1 over all the link's pairs -> no cross-lane
// reduction. srcs preloaded 10/group/batch, broadcast via __shfl; fixed-10
// unrolled inner loop keeps 10 independent gathers in flight.
__global__ void __launch_bounds__(256)
k_agg(const int* __restrict__ rs, const int* __restrict__ lid,
      const int* __restrict__ srcs,
      const unsigned char* __restrict__ X1b, const __half* __restrict__ X2h,
      float* __restrict__ agg) {
    const int wave = threadIdx.x >> 6;
    const int lane = threadIdx.x & 63;
    const int g = lane / 10;          // 0..5 active, 6 = idle (lanes 60-63)
    const int j = lane - g * 10;      // 0..9
    const int gsel = (g < 6) ? g : 5;
    const int slot = (blockIdx.x * 4 + wave) * 6 + gsel;

    const bool active = (g < 6) && (slot < N_LINKS);
    const int sc = min(slot, N_LINKS - 1);
    const int link = lid[sc];
    const int row_start = rs[sc];
    const int cnt = active ? (rs[sc + 1] - row_start) : 0;
    const int cl = (cnt > 0) ? (cnt - 1) : 0;

    const __half2 hv = *(const __half2*)(X2h + (size_t)link * F + 2 * j);
    const float x2a = __half2float(__low2half(hv));
    const float x2b = __half2float(__high2half(hv));

    // wave-max of cnt (cnt is group-uniform; idle lanes are 0)
    int cmax = cnt;
#pragma unroll
    for (int off = 1; off < 64; off <<= 1)
        cmax = max(cmax, __shfl_xor(cmax, off, 64));

    float acc_a = 0.0f, acc_b = 0.0f;

    for (int base = 0; base < cmax; base += 10) {
        const int sv = srcs[row_start + min(base + j, cl)];  // batch preload
#pragma unroll
        for (int r = 0; r < 10; ++r) {
            const int src = __shfl(sv, gsel * 10 + r, 64);   // prescaled src*20
            const unsigned v = *(const unsigned short*)(X1b + src + 2 * j);
            const f32x2 xx = __builtin_amdgcn_cvt_pk_f32_fp8((int)v, false);
            const bool ok = (base + r) < cnt;
            acc_a += ok ? selu_b(xx[0] + x2a) : 0.0f;
            acc_b += ok ? selu_b(xx[1] + x2b) : 0.0f;
        }
    }
    if (active) {
        float2 o; o.x = acc_a; o.y = acc_b;
        *(float2*)(agg + (size_t)link * F + 2 * j) = o;
    }
}

// GRU fused with next-iteration premsg (flags&1) and feature reduce (flags&2).
// Weights live in LDS as fp16 half2; all dot products use v_dot2_f32_f16
// (2 MACs/instr, f32 accumulate) -> LDS bytes and VALU count both halved.
__global__ void __launch_bounds__(256)
k_gru(const float* __restrict__ agg, const float* __restrict__ h_in,
      const float* __restrict__ W_ih, const float* __restrict__ W_hh,
      const float* __restrict__ b_ih, const float* __restrict__ b_hh,
      const float* __restrict__ W_msg, const float* __restrict__ b_msg,
      float* __restrict__ h_out, unsigned char* __restrict__ X1b,
      __half* __restrict__ X2h, float* __restrict__ feature, int flags) {
    __shared__ h16x2 WiH[3 * F * 10];   // row (g*F+j): 10 half2 = 20 weights
    __shared__ h16x2 WhH[3 * F * 10];
    __shared__ h16x2 WmH[F * 20];       // row o: k 0..9 = W1, 10..19 = W2
    __shared__ float bi[3 * F];
    __shared__ float bh[3 * F];
    __shared__ float bm[F];
    __shared__ float red[4 * F];
    {
        _Float16* wi = (_Float16*)WiH;
        _Float16* wh = (_Float16*)WhH;
        for (int i = threadIdx.x; i < 3 * F * F; i += blockDim.x) {
            wi[i] = (_Float16)W_ih[i];
            wh[i] = (_Float16)W_hh[i];
        }
        _Float16* wm = (_Float16*)WmH;
        for (int i = threadIdx.x; i < F * 2 * F; i += blockDim.x)
            wm[i] = (_Float16)W_msg[i];
    }
    if (threadIdx.x < 3 * F) {
        bi[threadIdx.x] = b_ih[threadIdx.x];
        bh[threadIdx.x] = b_hh[threadIdx.x];
    }
    if (threadIdx.x < F) bm[threadIdx.x] = b_msg[threadIdx.x];
    __syncthreads();

    const int l = blockIdx.x * blockDim.x + threadIdx.x;

    float m[F], h[F];
    const float4* mp = (const float4*)(agg  + (size_t)l * F);
    const float4* hp = (const float4*)(h_in + (size_t)l * F);
#pragma unroll
    for (int i = 0; i < 5; ++i) {
        float4 vm = mp[i], vh = hp[i];
        m[4*i+0] = vm.x; m[4*i+1] = vm.y; m[4*i+2] = vm.z; m[4*i+3] = vm.w;
        h[4*i+0] = vh.x; h[4*i+1] = vh.y; h[4*i+2] = vh.z; h[4*i+3] = vh.w;
    }
    h16x2 mh[10], hh[10];
#pragma unroll
    for (int i = 0; i < 10; ++i) {
        mh[i][0] = (_Float16)m[2*i]; mh[i][1] = (_Float16)m[2*i+1];
        hh[i][0] = (_Float16)h[2*i]; hh[i][1] = (_Float16)h[2*i+1];
    }

    float hn[F];
#pragma unroll
    for (int j = 0; j < F; ++j) {
        float gri = 0.f, gzi = 0.f, gin = bi[2*F + j];
        float grh = 0.f, gzh = 0.f, ghn = bh[2*F + j];
#pragma unroll
        for (int k = 0; k < 10; ++k) {
            gri = __builtin_amdgcn_fdot2(WiH[(0*F + j) * 10 + k], mh[k], gri, false);
            gzi = __builtin_amdgcn_fdot2(WiH[(1*F + j) * 10 + k], mh[k], gzi, false);
            gin = __builtin_amdgcn_fdot2(WiH[(2*F + j) * 10 + k], mh[k], gin, false);
            grh = __builtin_amdgcn_fdot2(WhH[(0*F + j) * 10 + k], hh[k], grh, false);
            gzh = __builtin_amdgcn_fdot2(WhH[(1*F + j) * 10 + k], hh[k], gzh, false);
            ghn = __builtin_amdgcn_fdot2(WhH[(2*F + j) * 10 + k], hh[k], ghn, false);
        }
        float r = sigmoid_f(bi[j] + bh[j] + gri + grh);
        float z = sigmoid_f(bi[F + j] + bh[F + j] + gzi + gzh);
        float n = tanh_fast(gin + r * ghn);
        hn[j] = (1.0f - z) * n + z * h[j];
    }

    float4* op = (float4*)(h_out + (size_t)l * F);
#pragma unroll
    for (int i = 0; i < 5; ++i)
        op[i] = make_float4(hn[4*i], hn[4*i+1], hn[4*i+2], hn[4*i+3]);

    if (flags & 1) {  // premsg for next iteration from hn
        h16x2 hnh[10];
#pragma unroll
        for (int i = 0; i < 10; ++i) {
            hnh[i][0] = (_Float16)hn[2*i]; hnh[i][1] = (_Float16)hn[2*i+1];
        }
        float o1[F], o2[F];
#pragma unroll
        for (int o = 0; o < F; ++o) {
            float a1 = bm[o], a2 = 0.0f;
#pragma unroll
            for (int k = 0; k < 10; ++k) {
                a1 = __builtin_amdgcn_fdot2(WmH[o * 20 + k],      hnh[k], a1, false);
                a2 = __builtin_amdgcn_fdot2(WmH[o * 20 + 10 + k], hnh[k], a2, false);
            }
            o1[o] = a1; o2[o] = a2;
        }
        store_row_fp8(X1b + (size_t)l * XB, o1);
        __half2* xp = (__half2*)(X2h + (size_t)l * F);
#pragma unroll
        for (int i = 0; i < 10; ++i)
            xp[i] = __halves2half2(__float2half(o2[2*i]), __float2half(o2[2*i+1]));
    }

    if (flags & 2) {  // feature reduction: sum hn over all links
#pragma unroll
        for (int off = 1; off < 64; off <<= 1) {
#pragma unroll
            for (int j = 0; j < F; ++j) hn[j] += __shfl_xor(hn[j], off, 64);
        }
        const int lane = threadIdx.x & 63;
        const int wave = threadIdx.x >> 6;
        if (lane == 0) {
#pragma unroll
            for (int j = 0; j < F; ++j) red[wave * F + j] = hn[j];
        }
        __syncthreads();
        if (threadIdx.x < F) {
            float s = red[threadIdx.x] + red[F + threadIdx.x] +
                      red[2 * F + threadIdx.x] + red[3 * F + threadIdx.x];
            atomicAdd(&feature[threadIdx.x], s);
        }
    }
}

__global__ void k_readout(const float* __restrict__ feature,
                          const float* __restrict__ W_r1, const float* __restrict__ b_r1,
                          const float* __restrict__ W_r2, const float* __restrict__ b_r2,
                          const float* __restrict__ W_out, const float* __restrict__ b_out,
                          float* __restrict__ out) {
    if (threadIdx.x != 0 || blockIdx.x != 0) return;
    float fv[F], h1[F], h2[F];
#pragma unroll
    for (int i = 0; i < F; ++i) fv[i] = feature[i];
#pragma unroll
    for (int o = 0; o < F; ++o) {
        float a = b_r1[o];
#pragma unroll
        for (int k = 0; k < F; ++k) a = fmaf(W_r1[o * F + k], fv[k], a);
        h1[o] = selu_f(a);
    }
#pragma unroll
    for (int o = 0; o < F; ++o) {
        float a = b_r2[o];
#pragma unroll
        for (int k = 0; k < F; ++k) a = fmaf(W_r2[o * F + k], h1[k], a);
        h2[o] = selu_f(a);
    }
    float a = b_out[0];
#pragma unroll
    for (int k = 0; k < F; ++k) a = fmaf(W_out[k], h2[k], a);
    out[0] = a;
}

extern "C" void kernel_launch(void* const* d_in, const int* in_sizes, int n_in,
                              void* d_out, int out_size, void* d_ws, size_t ws_size,
                              hipStream_t stream) {
    const float* link_state = (const float*)d_in[0];
    const int*   first      = (const int*)  d_in[1];
    const int*   second     = (const int*)  d_in[2];
    // d_in[3] = state_dim (unused)
    const float* W_msg = (const float*)d_in[4];
    const float* b_msg = (const float*)d_in[5];
    const float* W_ih  = (const float*)d_in[6];
    const float* W_hh  = (const float*)d_in[7];
    const float* b_ih  = (const float*)d_in[8];
    const float* b_hh  = (const float*)d_in[9];
    const float* W_r1  = (const float*)d_in[10];
    const float* b_r1  = (const float*)d_in[11];
    const float* W_r2  = (const float*)d_in[12];
    const float* b_r2  = (const float*)d_in[13];
    const float* W_out = (const float*)d_in[14];
    const float* b_out = (const float*)d_in[15];
    float* out = (float*)d_out;

    const size_t NF = (size_t)N_LINKS * F;
    float* state   = (float*)d_ws;                    // 21 MB
    float* agg     = state + NF;                      // 21 MB (aliases ent)
    unsigned char* X1b = (unsigned char*)(agg + NF);  // 5.25 MB (20B fp8 rows)
    __half* X2h    = (__half*)(X1b + (size_t)N_LINKS * XB + 64);  // 10.5 MB
    int*    srcs   = (int*)(X2h + NF);                // 16.8 MB
    int*    rs     = srcs + N_PAIRS;                  // 1 MB (+1)
    int*    lid    = rs + N_LINKS + 1;                // 1 MB
    float* feature = (float*)(lid + N_LINKS);         // 128 B slot
    int* ptable    = (int*)(feature + 32);            // 256*(256+1) ints
    int* sectot    = ptable + PB * (NSB + 1);         // 256 ints
    int* sbase     = sectot + NSB;                    // 257 ints
    int* ent       = (int*)agg;                       // lifetime: part..build only

    hipMemsetAsync(sectot, 0, NSB * sizeof(int), stream);
    hipMemsetAsync(feature, 0, F * sizeof(float), stream);

    k_part<<<PB, PT, 0, stream>>>(first, second, ent, ptable, sectot);
    k_scan256<<<1, NSB, 0, stream>>>(sectot, sbase, rs);
    k_build<<<NSB, PT, 0, stream>>>(ptable, sbase, ent, srcs, rs, lid);

    k_premsg<<<N_LINKS / 256, 256, 0, stream>>>(link_state, W_msg, b_msg, X1b, X2h);
    const int aggBlocks = (N_LINKS + 23) / 24;   // 4 waves x 6 links per block
    for (int t = 0; t < T_ITERS; ++t) {
        const float* h = (t == 0) ? link_state : state;
        int flags = (t < T_ITERS - 1 ? 1 : 0) | (t == T_ITERS - 1 ? 2 : 0);
        k_agg<<<aggBlocks, 256, 0, stream>>>(rs, lid, srcs, X1b, X2h, agg);
        k_gru<<<N_LINKS / 256, 256, 0, stream>>>(agg, h, W_ih, W_hh, b_ih, b_hh,
                                                 W_msg, b_msg, state, X1b, X2h,
                                                 feature, flags);
    }
    k_readout<<<1, 64, 0, stream>>>(feature, W_r1, b_r1, W_r2, b_r2, W_out, b_out, out);
}

// Round 19
// 560.725 us; speedup vs baseline: 1.3368x; 1.0409x over previous
//
#include <hip/hip_runtime.h>
#include <hip/hip_fp16.h>

#define N_LINKS 262144
#define N_PAIRS 4194304
#define F 20
#define XB 20                   // X1 fp8 row stride in BYTES (packed, no pad)
#define T_ITERS 4

#define NSB 256                 // sectors (CSR build): sector = link >> 10
#define LPS 1024                // links per sector
#define PB 256                  // partition blocks
#define PT 1024                 // partition threads
#define PCHUNK (N_PAIRS / PB)   // 16384 pairs per partition block
#define PPT (PCHUNK / PT)       // 16 pairs per thread

typedef float f32x2 __attribute__((ext_vector_type(2)));
typedef _Float16 h16x2 __attribute__((ext_vector_type(2)));

__device__ __forceinline__ float selu_f(float x) {
    const float scale = 1.0507009873554805f;
    const float scale_alpha = 1.7580993408473766f;  // scale * alpha
    return x > 0.0f ? scale * x : scale_alpha * (__expf(x) - 1.0f);
}

// Branchless selu: sa*exp(min(x,0)) - sa + s*max(x,0). Exact at x=0 (exp(0)=1).
__device__ __forceinline__ float selu_b(float x) {
    const float s = 1.0507009873554805f;
    const float sa = 1.7580993408473766f;
    const float mx = fmaxf(x, 0.0f);
    const float mn = fminf(x, 0.0f);
    return fmaf(sa, __expf(mn), fmaf(s, mx, -sa));
}

__device__ __forceinline__ float sigmoid_f(float x) {
    return 1.0f / (1.0f + __expf(-x));
}

__device__ __forceinline__ float tanh_fast(float x) {
    x = fminf(fmaxf(x, -15.0f), 15.0f);
    float e = __expf(2.0f * x);
    return (e - 1.0f) / (e + 1.0f);
}

// Pack 20 floats -> 20 fp8 e4m3 bytes, one 20B row (5 dword stores, 4B aligned).
__device__ __forceinline__ void store_row_fp8(unsigned char* rowp, const float* o1) {
    int* p = (int*)rowp;
#pragma unroll
    for (int i = 0; i < 5; ++i) {
        int w = 0;
        w = __builtin_amdgcn_cvt_pk_fp8_f32(o1[4*i+0], o1[4*i+1], w, false);
        w = __builtin_amdgcn_cvt_pk_fp8_f32(o1[4*i+2], o1[4*i+3], w, true);
        p[i] = w;
    }
}

// ---------------- CSR build (once per call; graph is static) ----------------

// Each block counting-sorts its 16K-pair chunk by sector into its OWN window
// of `ent`. Emits per-(block,sector) offsets + global sector totals.
// Entry = {first:18 | link-within-sector:10}.
__global__ void __launch_bounds__(PT)
k_part(const int* __restrict__ first, const int* __restrict__ second,
       int* __restrict__ ent, int* __restrict__ ptable, int* __restrict__ sectot) {
    __shared__ int hist[NSB];
    __shared__ int cur[NSB];
    const int b = blockIdx.x;
    const int cbase = b * PCHUNK;
    const int tid = threadIdx.x;
    for (int i = tid; i < NSB; i += PT) hist[i] = 0;
    __syncthreads();
    int sv[PPT];
#pragma unroll
    for (int k = 0; k < PPT; ++k) {
        sv[k] = second[cbase + k * PT + tid];
        atomicAdd(&hist[sv[k] >> 10], 1);
    }
    __syncthreads();
    if (tid < NSB) {
        int acc = 0;
        for (int j = 0; j < tid; ++j) acc += hist[j];   // excl scan, 256 bins
        cur[tid] = acc;
        ptable[b * (NSB + 1) + tid] = acc;
        if (tid == 0) ptable[b * (NSB + 1) + NSB] = PCHUNK;
        atomicAdd(&sectot[tid], hist[tid]);
    }
    __syncthreads();
#pragma unroll
    for (int k = 0; k < PPT; ++k) {
        const int s = sv[k];
        const int f = first[cbase + k * PT + tid];
        const int pos = atomicAdd(&cur[s >> 10], 1);
        ent[cbase + pos] = f | ((s & 1023) << 18);
    }
}

// Exact exclusive scan of 256 sector totals -> sector bases (srcs contiguous).
__global__ void k_scan256(const int* __restrict__ sectot, int* __restrict__ sbase,
                          int* __restrict__ rs) {
    __shared__ int s[NSB];
    const int t = threadIdx.x;
    s[t] = sectot[t];
    __syncthreads();
    if (t == 0) {
        int acc = 0;
        for (int j = 0; j < NSB; ++j) { int c = s[j]; s[j] = acc; acc += c; }
    }
    __syncthreads();
    sbase[t] = s[t];
    if (t == 0) { sbase[NSB] = N_PAIRS; rs[N_LINKS] = N_PAIRS; }
}

// One block per sector: gather the sector's entries from the table-addressed
// runs, per-link LDS histogram, DEGREE-SORT the 1024 links (counting sort,
// 64 bins) -> rank order. rs/srcs are emitted in rank order; lid[rank] gives
// the true link id. Waves in k_agg then see near-uniform degrees.
// srcs entries are PRESCALED: src * 20 (byte base into X1b).
__global__ void __launch_bounds__(PT)
k_build(const int* __restrict__ ptable, const int* __restrict__ sbase,
        const int* __restrict__ ent, int* __restrict__ srcs, int* __restrict__ rs,
        int* __restrict__ lid) {
    __shared__ int rstart[PB];
    __shared__ int rlen[PB];
    __shared__ int lcnt[LPS];
    __shared__ int cur[LPS];
    __shared__ int dhist[64];
    __shared__ int dbase[64];
    __shared__ int dcur[64];
    const int sb = blockIdx.x;
    const int tid = threadIdx.x;
    if (tid < PB) {
        const int o0 = ptable[tid * (NSB + 1) + sb];
        const int o1 = ptable[tid * (NSB + 1) + sb + 1];
        rstart[tid] = tid * PCHUNK + o0;
        rlen[tid] = o1 - o0;
    }
    lcnt[tid] = 0;                       // PT == LPS
    if (tid < 64) { dhist[tid] = 0; dcur[tid] = 0; }
    __syncthreads();
    const int wave = tid >> 6;
    const int lane = tid & 63;
    for (int j = wave; j < PB; j += (PT >> 6)) {
        const int r0 = rstart[j], rl = rlen[j];
        for (int i = lane; i < rl; i += 64)
            atomicAdd(&lcnt[(ent[r0 + i] >> 18) & 1023], 1);
    }
    __syncthreads();
    const int count = lcnt[tid];
    const int dbin = min(count, 63);
    atomicAdd(&dhist[dbin], 1);
    __syncthreads();
    if (tid == 0) {
        int acc = 0;
        for (int b = 0; b < 64; ++b) { dbase[b] = acc; acc += dhist[b]; }
    }
    __syncthreads();
    const int rank = dbase[dbin] + atomicAdd(&dcur[dbin], 1);
    lcnt[rank] = count;                  // re-key counts into rank order
    lid[sb * LPS + rank] = sb * LPS + tid;
    __syncthreads();
    for (int off = 1; off < LPS; off <<= 1) {   // inclusive Hillis-Steele scan
        const int v = (tid >= off) ? lcnt[tid - off] : 0;
        __syncthreads();
        lcnt[tid] += v;
        __syncthreads();
    }
    const int sbb = sbase[sb];
    const int excl = lcnt[rank] - count;
    rs[sb * LPS + rank] = sbb + excl;
    cur[tid] = excl;                     // cur stays in tid (link) space
    __syncthreads();
    for (int j = wave; j < PB; j += (PT >> 6)) {
        const int r0 = rstart[j], rl = rlen[j];
        for (int i = lane; i < rl; i += 64) {
            const int e = ent[r0 + i];
            const int pos = atomicAdd(&cur[(e >> 18) & 1023], 1);
            srcs[sbb + pos] = (e & 0x3FFFF) * 20;   // prescaled byte base
        }
    }
}

// ---------------- per-iteration kernels ----------------

// X1b[l] = fp8(W1 @ state[l] + b_msg), 20B rows ; X2h[l] = fp16(W2 @ state[l]);
// also writes st16[l] = fp16(link_state[l]) so k_gru runs a single fp16 path.
__global__ void k_premsg(const float* __restrict__ state,
                         const float* __restrict__ W_msg,
                         const float* __restrict__ b_msg,
                         unsigned char* __restrict__ X1b, __half* __restrict__ X2h,
                         __half* __restrict__ st16) {
    __shared__ float Wl[F * 2 * F];
    __shared__ float bl[F];
    for (int i = threadIdx.x; i < F * 2 * F; i += blockDim.x) Wl[i] = W_msg[i];
    if (threadIdx.x < F) bl[threadIdx.x] = b_msg[threadIdx.x];
    __syncthreads();

    int l = blockIdx.x * blockDim.x + threadIdx.x;

    float s[F];
    const float4* sp = (const float4*)(state + (size_t)l * F);
#pragma unroll
    for (int i = 0; i < 5; ++i) {
        float4 v = sp[i];
        s[4*i+0] = v.x; s[4*i+1] = v.y; s[4*i+2] = v.z; s[4*i+3] = v.w;
    }
    __half2* so = (__half2*)(st16 + (size_t)l * F);
#pragma unroll
    for (int i = 0; i < 10; ++i)
        so[i] = __halves2half2(__float2half(s[2*i]), __float2half(s[2*i+1]));

    float o1[F], o2[F];
#pragma unroll
    for (int o = 0; o < F; ++o) {
        float a1 = bl[o], a2 = 0.0f;
#pragma unroll
        for (int k = 0; k < F; ++k) {
            a1 = fmaf(Wl[o * 2 * F + k],     s[k], a1);
            a2 = fmaf(Wl[o * 2 * F + F + k], s[k], a2);
        }
        o1[o] = a1; o2[o] = a2;
    }
    store_row_fp8(X1b + (size_t)l * XB, o1);
    __half2* xp = (__half2*)(X2h + (size_t)l * F);
#pragma unroll
    for (int i = 0; i < 10; ++i)
        xp[i] = __halves2half2(__float2half(o2[2*i]), __float2half(o2[2*i+1]));
}

// Gather-aggregate, 6 RANK-consecutive links per wave (degree-sorted -> the 6
// links have near-equal degree). lane = g*10 + j; group g owns rank slot lb+g
// (true link = lid[slot]); lane j accumulates features 2j,2j+1 over all the
// link's pairs -> no cross-lane reduction. Output agg is fp16 (half2 store).
__global__ void __launch_bounds__(256)
k_agg(const int* __restrict__ rs, const int* __restrict__ lid,
      const int* __restrict__ srcs,
      const unsigned char* __restrict__ X1b, const __half* __restrict__ X2h,
      __half* __restrict__ aggh) {
    const int wave = threadIdx.x >> 6;
    const int lane = threadIdx.x & 63;
    const int g = lane / 10;          // 0..5 active, 6 = idle (lanes 60-63)
    const int j = lane - g * 10;      // 0..9
    const int gsel = (g < 6) ? g : 5;
    const int slot = (blockIdx.x * 4 + wave) * 6 + gsel;

    const bool active = (g < 6) && (slot < N_LINKS);
    const int sc = min(slot, N_LINKS - 1);
    const int link = lid[sc];
    const int row_start = rs[sc];
    const int cnt = active ? (rs[sc + 1] - row_start) : 0;
    const int cl = (cnt > 0) ? (cnt - 1) : 0;

    const __half2 hv = *(const __half2*)(X2h + (size_t)link * F + 2 * j);
    const float x2a = __half2float(__low2half(hv));
    const float x2b = __half2float(__high2half(hv));

    // wave-max of cnt (cnt is group-uniform; idle lanes are 0)
    int cmax = cnt;
#pragma unroll
    for (int off = 1; off < 64; off <<= 1)
        cmax = max(cmax, __shfl_xor(cmax, off, 64));

    float acc_a = 0.0f, acc_b = 0.0f;

    for (int base = 0; base < cmax; base += 10) {
        const int sv = srcs[row_start + min(base + j, cl)];  // batch preload
#pragma unroll
        for (int r = 0; r < 10; ++r) {
            const int src = __shfl(sv, gsel * 10 + r, 64);   // prescaled src*20
            const unsigned v = *(const unsigned short*)(X1b + src + 2 * j);
            const f32x2 xx = __builtin_amdgcn_cvt_pk_f32_fp8((int)v, false);
            const bool ok = (base + r) < cnt;
            acc_a += ok ? selu_b(xx[0] + x2a) : 0.0f;
            acc_b += ok ? selu_b(xx[1] + x2b) : 0.0f;
        }
    }
    if (active) {
        *(__half2*)(aggh + (size_t)link * F + 2 * j) =
            __halves2half2(__float2half(acc_a), __float2half(acc_b));
    }
}

// GRU fused with next-iteration premsg (flags&1) and feature reduce (flags&2).
// agg and state are fp16 (halved stream bytes: 79 -> 47 MB/iter). Weights in
// LDS as fp16 half2; dot products via v_dot2_f32_f16 (f32 accumulate). hn is
// kept fp32 in registers for the premsg and the feature sum.
__global__ void __launch_bounds__(256)
k_gru(const __half* __restrict__ aggh, const __half* __restrict__ h_in,
      const float* __restrict__ W_ih, const float* __restrict__ W_hh,
      const float* __restrict__ b_ih, const float* __restrict__ b_hh,
      const float* __restrict__ W_msg, const float* __restrict__ b_msg,
      __half* __restrict__ h_out, unsigned char* __restrict__ X1b,
      __half* __restrict__ X2h, float* __restrict__ feature, int flags) {
    __shared__ h16x2 WiH[3 * F * 10];   // row (g*F+j): 10 half2 = 20 weights
    __shared__ h16x2 WhH[3 * F * 10];
    __shared__ h16x2 WmH[F * 20];       // row o: k 0..9 = W1, 10..19 = W2
    __shared__ float bi[3 * F];
    __shared__ float bh[3 * F];
    __shared__ float bm[F];
    __shared__ float red[4 * F];
    {
        _Float16* wi = (_Float16*)WiH;
        _Float16* wh = (_Float16*)WhH;
        for (int i = threadIdx.x; i < 3 * F * F; i += blockDim.x) {
            wi[i] = (_Float16)W_ih[i];
            wh[i] = (_Float16)W_hh[i];
        }
        _Float16* wm = (_Float16*)WmH;
        for (int i = threadIdx.x; i < F * 2 * F; i += blockDim.x)
            wm[i] = (_Float16)W_msg[i];
    }
    if (threadIdx.x < 3 * F) {
        bi[threadIdx.x] = b_ih[threadIdx.x];
        bh[threadIdx.x] = b_hh[threadIdx.x];
    }
    if (threadIdx.x < F) bm[threadIdx.x] = b_msg[threadIdx.x];
    __syncthreads();

    const int l = blockIdx.x * blockDim.x + threadIdx.x;

    h16x2 mh[10], hh[10];
    const h16x2* mp = (const h16x2*)(aggh + (size_t)l * F);
    const h16x2* hp = (const h16x2*)(h_in + (size_t)l * F);
#pragma unroll
    for (int i = 0; i < 10; ++i) {
        mh[i] = mp[i];
        hh[i] = hp[i];
    }

    float hn[F];
#pragma unroll
    for (int j = 0; j < F; ++j) {
        float gri = 0.f, gzi = 0.f, gin = bi[2*F + j];
        float grh = 0.f, gzh = 0.f, ghn = bh[2*F + j];
#pragma unroll
        for (int k = 0; k < 10; ++k) {
            gri = __builtin_amdgcn_fdot2(WiH[(0*F + j) * 10 + k], mh[k], gri, false);
            gzi = __builtin_amdgcn_fdot2(WiH[(1*F + j) * 10 + k], mh[k], gzi, false);
            gin = __builtin_amdgcn_fdot2(WiH[(2*F + j) * 10 + k], mh[k], gin, false);
            grh = __builtin_amdgcn_fdot2(WhH[(0*F + j) * 10 + k], hh[k], grh, false);
            gzh = __builtin_amdgcn_fdot2(WhH[(1*F + j) * 10 + k], hh[k], gzh, false);
            ghn = __builtin_amdgcn_fdot2(WhH[(2*F + j) * 10 + k], hh[k], ghn, false);
        }
        float r = sigmoid_f(bi[j] + bh[j] + gri + grh);
        float z = sigmoid_f(bi[F + j] + bh[F + j] + gzi + gzh);
        float n = tanh_fast(gin + r * ghn);
        const float hO = (float)hh[j >> 1][j & 1];
        hn[j] = (1.0f - z) * n + z * hO;
    }

    __half2* op = (__half2*)(h_out + (size_t)l * F);
#pragma unroll
    for (int i = 0; i < 10; ++i)
        op[i] = __halves2half2(__float2half(hn[2*i]), __float2half(hn[2*i+1]));

    if (flags & 1) {  // premsg for next iteration from hn
        h16x2 hnh[10];
#pragma unroll
        for (int i = 0; i < 10; ++i) {
            hnh[i][0] = (_Float16)hn[2*i]; hnh[i][1] = (_Float16)hn[2*i+1];
        }
        float o1[F], o2[F];
#pragma unroll
        for (int o = 0; o < F; ++o) {
            float a1 = bm[o], a2 = 0.0f;
#pragma unroll
            for (int k = 0; k < 10; ++k) {
                a1 = __builtin_amdgcn_fdot2(WmH[o * 20 + k],      hnh[k], a1, false);
                a2 = __builtin_amdgcn_fdot2(WmH[o * 20 + 10 + k], hnh[k], a2, false);
            }
            o1[o] = a1; o2[o] = a2;
        }
        store_row_fp8(X1b + (size_t)l * XB, o1);
        __half2* xp = (__half2*)(X2h + (size_t)l * F);
#pragma unroll
        for (int i = 0; i < 10; ++i)
            xp[i] = __halves2half2(__float2half(o2[2*i]), __float2half(o2[2*i+1]));
    }

    if (flags & 2) {  // feature reduction: sum hn over all links
#pragma unroll
        for (int off = 1; off < 64; off <<= 1) {
#pragma unroll
            for (int j = 0; j < F; ++j) hn[j] += __shfl_xor(hn[j], off, 64);
        }
        const int lane = threadIdx.x & 63;
        const int wave = threadIdx.x >> 6;
        if (lane == 0) {
#pragma unroll
            for (int j = 0; j < F; ++j) red[wave * F + j] = hn[j];
        }
        __syncthreads();
        if (threadIdx.x < F) {
            float s = red[threadIdx.x] + red[F + threadIdx.x] +
                      red[2 * F + threadIdx.x] + red[3 * F + threadIdx.x];
            atomicAdd(&feature[threadIdx.x], s);
        }
    }
}

__global__ void k_readout(const float* __restrict__ feature,
                          const float* __restrict__ W_r1, const float* __restrict__ b_r1,
                          const float* __restrict__ W_r2, const float* __restrict__ b_r2,
                          const float* __restrict__ W_out, const float* __restrict__ b_out,
                          float* __restrict__ out) {
    if (threadIdx.x != 0 || blockIdx.x != 0) return;
    float fv[F], h1[F], h2[F];
#pragma unroll
    for (int i = 0; i < F; ++i) fv[i] = feature[i];
#pragma unroll
    for (int o = 0; o < F; ++o) {
        float a = b_r1[o];
#pragma unroll
        for (int k = 0; k < F; ++k) a = fmaf(W_r1[o * F + k], fv[k], a);
        h1[o] = selu_f(a);
    }
#pragma unroll
    for (int o = 0; o < F; ++o) {
        float a = b_r2[o];
#pragma unroll
        for (int k = 0; k < F; ++k) a = fmaf(W_r2[o * F + k], h1[k], a);
        h2[o] = selu_f(a);
    }
    float a = b_out[0];
#pragma unroll
    for (int k = 0; k < F; ++k) a = fmaf(W_out[k], h2[k], a);
    out[0] = a;
}

extern "C" void kernel_launch(void* const* d_in, const int* in_sizes, int n_in,
                              void* d_out, int out_size, void* d_ws, size_t ws_size,
                              hipStream_t stream) {
    const float* link_state = (const float*)d_in[0];
    const int*   first      = (const int*)  d_in[1];
    const int*   second     = (const int*)  d_in[2];
    // d_in[3] = state_dim (unused)
    const float* W_msg = (const float*)d_in[4];
    const float* b_msg = (const float*)d_in[5];
    const float* W_ih  = (const float*)d_in[6];
    const float* W_hh  = (const float*)d_in[7];
    const float* b_ih  = (const float*)d_in[8];
    const float* b_hh  = (const float*)d_in[9];
    const float* W_r1  = (const float*)d_in[10];
    const float* b_r1  = (const float*)d_in[11];
    const float* W_r2  = (const float*)d_in[12];
    const float* b_r2  = (const float*)d_in[13];
    const float* W_out = (const float*)d_in[14];
    const float* b_out = (const float*)d_in[15];
    float* out = (float*)d_out;

    const size_t NF = (size_t)N_LINKS * F;
    __half* st16 = (__half*)d_ws;                     // 10.5 MB (fp16 state)
    __half* aggh = st16 + NF;                         // 10.5 MB (fp16 agg)
    unsigned char* X1b = (unsigned char*)(aggh + NF); // 5.25 MB (20B fp8 rows)
    __half* X2h   = (__half*)(X1b + (size_t)N_LINKS * XB + 64);  // 10.5 MB
    int*    srcs  = (int*)(X2h + NF);                 // 16.8 MB
    int*    rs    = srcs + N_PAIRS;                   // 1 MB (+1)
    int*    lid   = rs + N_LINKS + 1;                 // 1 MB
    float* feature = (float*)(lid + N_LINKS);         // 128 B slot
    int* ptable   = (int*)(feature + 32);             // 256*(256+1) ints
    int* sectot   = ptable + PB * (NSB + 1);          // 256 ints
    int* sbase    = sectot + NSB;                     // 257 ints
    int* ent      = (int*)st16;   // aliases st16+aggh (21 MB); dead after build

    hipMemsetAsync(sectot, 0, NSB * sizeof(int), stream);
    hipMemsetAsync(feature, 0, F * sizeof(float), stream);

    k_part<<<PB, PT, 0, stream>>>(first, second, ent, ptable, sectot);
    k_scan256<<<1, NSB, 0, stream>>>(sectot, sbase, rs);
    k_build<<<NSB, PT, 0, stream>>>(ptable, sbase, ent, srcs, rs, lid);

    k_premsg<<<N_LINKS / 256, 256, 0, stream>>>(link_state, W_msg, b_msg,
                                                X1b, X2h, st16);
    const int aggBlocks = (N_LINKS + 23) / 24;   // 4 waves x 6 links per block
    for (int t = 0; t < T_ITERS; ++t) {
        int flags = (t < T_ITERS - 1 ? 1 : 0) | (t == T_ITERS - 1 ? 2 : 0);
        k_agg<<<aggBlocks, 256, 0, stream>>>(rs, lid, srcs, X1b, X2h, aggh);
        k_gru<<<N_LINKS / 256, 256, 0, stream>>>(aggh, st16, W_ih, W_hh, b_ih, b_hh,
                                                 W_msg, b_msg, st16, X1b, X2h,
                                                 feature, flags);
    }
    k_readout<<<1, 64, 0, stream>>>(feature, W_r1, b_r1, W_r2, b_r2, W_out, b_out, out);
}